// Round 5
// baseline (22.940 us; speedup 1.0000x reference)
//
#include <hip/hip_runtime.h>
#include <math.h>

#define NQ 8
#define NL 3
#define NC 3
#define BATCH 16384

// Layout l=5: 32 lanes/element, 8 complex amps per lane.
// Storage index t[7:0]: bits 0..2 = reg r, bits 3..7 = lane q bits 0..4.
// Lazy-CNOT frames: after k chains, frame A=L^k; gate on wire w acts along
// u_w = A^{-1} e_w with role sign g_w = row_w(A). No CNOT data movement.
//   L: B0=b1^..^b7, Bk=b0^..^bk.  L^-1 cols: u0={0,1},uk={k,k+1},u7={0,1,7}.
// All xor-lane exchanges with mask<16 via DPP (VALU); mask>=16 via ds_swizzle.

__device__ __forceinline__ int par(int x) { return __popc(x) & 1; }

template<int CTRL>
__device__ __forceinline__ float dppmov(float v) {
  return __builtin_bit_cast(float,
    __builtin_amdgcn_update_dpp(0, __builtin_bit_cast(int, v), CTRL, 0xF, 0xF, true));
}

// exchange with lane (q ^ M) within 32-lane group
template<int M>
__device__ __forceinline__ float xl(float v) {
  if constexpr (M >= 16) {
    return __builtin_bit_cast(float,
      __builtin_amdgcn_ds_swizzle(__builtin_bit_cast(int, v), (M << 10) | 0x1F));
  } else {
    constexpr int hi = M & 12;
    constexpr int first = (hi == 0) ? 0 : (hi == 4) ? 0x141    // row_half_mirror = xor7
                          : (hi == 8) ? 0x128                  // row_ror:8      = xor8
                          : 0x140;                             // row_mirror     = xor15
    constexpr int qx = (hi == 4 || hi == 12) ? ((M & 3) ^ 3) : (M & 3);
    constexpr int qc = (qx == 1) ? 0xB1 : (qx == 2) ? 0x4E : 0x1B;
    float t = v;
    if constexpr (first != 0) t = dppmov<first>(t);
    if constexpr (qx != 0)    t = dppmov<qc>(t);
    return t;
  }
}

// RY along pure-register direction UREG, role row (GREG, GLANE)
template<int UREG, int GREG, int GLANE>
__device__ __forceinline__ void ry_rr(float (&sr)[8], float (&si)[8],
                                      float c, float s, int q) {
  const float sl = par(q & GLANE) ? s : -s;
  #pragma unroll
  for (int rA = 0; rA < 8; ++rA) {
    if (rA < (rA ^ UREG)) {
      const int rB = rA ^ UREG;
      const float FA = par(rA & GREG) ? -sl : sl;   // note: <g,u>=1 => FB=-FA
      const float ar = sr[rA], ai = si[rA];
      sr[rA] = c * ar + FA * sr[rB];
      si[rA] = c * ai + FA * si[rB];
      sr[rB] = c * sr[rB] - FA * ar;
      si[rB] = c * si[rB] - FA * ai;
    }
  }
}

// RY along pure-lane direction ULANE
template<int ULANE, int GREG, int GLANE>
__device__ __forceinline__ void ry_ll(float (&sr)[8], float (&si)[8],
                                      float c, float s, int q) {
  const float sl = par(q & GLANE) ? s : -s;
  #pragma unroll
  for (int r = 0; r < 8; ++r) {
    const float xr = xl<ULANE>(sr[r]);
    const float xi = xl<ULANE>(si[r]);
    const float F  = par(r & GREG) ? -sl : sl;
    sr[r] = c * sr[r] + F * xr;
    si[r] = c * si[r] + F * xi;
  }
}

// RY along mixed direction (UREG, ULANE)
template<int UREG, int ULANE, int GREG, int GLANE>
__device__ __forceinline__ void ry_mix(float (&sr)[8], float (&si)[8],
                                       float c, float s, int q) {
  constexpr int RFLIP = __builtin_popcount(GREG & UREG) & 1;
  const float sl = par(q & GLANE) ? s : -s;
  #pragma unroll
  for (int rA = 0; rA < 8; ++rA) {
    if (rA < (rA ^ UREG)) {
      const int rB = rA ^ UREG;
      const float pBr = xl<ULANE>(sr[rB]);   // partner of (q,rA) at (q^UL,rB)
      const float pBi = xl<ULANE>(si[rB]);
      const float pAr = xl<ULANE>(sr[rA]);   // partner of (q,rB)
      const float pAi = xl<ULANE>(si[rA]);
      const float FA = par(rA & GREG) ? -sl : sl;
      const float FB = RFLIP ? -FA : FA;
      sr[rA] = c * sr[rA] + FA * pBr;
      si[rA] = c * si[rA] + FA * pBi;
      sr[rB] = c * sr[rB] + FB * pAr;
      si[rB] = c * si[rB] + FB * pAi;
    }
  }
}

__global__ __launch_bounds__(256, 8) void vqc_kernel(
    const float* __restrict__ x, const float* __restrict__ qw,
    const float* __restrict__ W, const float* __restrict__ b,
    float* __restrict__ out)
{
  const int tid  = threadIdx.x;
  const int q    = tid & 31;
  const int elem = blockIdx.x * 8 + (tid >> 5);

  const float PI = 3.14159265358979323846f;

  float xs[8];
  {
    const float4 x0 = *(const float4*)(x + elem * 8);
    const float4 x1 = *(const float4*)(x + elem * 8 + 4);
    xs[0] = x0.x; xs[1] = x0.y; xs[2] = x0.z; xs[3] = x0.w;
    xs[4] = x1.x; xs[5] = x1.y; xs[6] = x1.z; xs[7] = x1.w;
  }

  float sr[8], si[8];

  // =============== layer 0: RY (frame I) -> product state (real) ===============
  {
    float cw[8], sv[8];
    #pragma unroll
    for (int w = 0; w < 8; ++w)
      __sincosf(0.5f * (PI * xs[w] + qw[w]), &sv[w], &cw[w]);

    float P = ((q & 1)  ? sv[3] : cw[3]);
    P      *= ((q & 2)  ? sv[4] : cw[4]);
    P      *= ((q & 4)  ? sv[5] : cw[5]);
    P      *= ((q & 8)  ? sv[6] : cw[6]);
    P      *= ((q & 16) ? sv[7] : cw[7]);
    sr[0] = P * cw[0];
    sr[1] = P * sv[0];
    #pragma unroll
    for (int r = 0; r < 2; ++r) { sr[r + 2] = sr[r] * sv[1]; sr[r] *= cw[1]; }
    #pragma unroll
    for (int r = 0; r < 4; ++r) { sr[r + 4] = sr[r] * sv[2]; sr[r] *= cw[2]; }
  }

  // ===== lazy CNOT #1 (free) ; RZ layer 0 in frame L (real -> complex) =====
  // rows of L: reg masks {6,3,7,7,7,7,7,7}, lane masks {31,0,0,1,3,7,15,31}
  {
    const float h0 = 0.5f * qw[8],  h1 = 0.5f * qw[9];
    const float h2 = 0.5f * qw[10], h3 = 0.5f * qw[11];
    const float h4 = 0.5f * qw[12], h5 = 0.5f * qw[13];
    const float h6 = 0.5f * qw[14], h7 = 0.5f * qw[15];
    const float a0 = par(q & 31) ? h0 : -h0;
    const float a1 = -h1;
    const float A7 = -h2 + (par(q & 1)  ? h3 : -h3) + (par(q & 3)  ? h4 : -h4)
                         + (par(q & 7)  ? h5 : -h5) + (par(q & 15) ? h6 : -h6)
                         + (par(q & 31) ? h7 : -h7);
    // phi[r] = a0*sg(r&6) + a1*sg(r&3) + A7*sg(r&7); phi[r^2] = -phi[r]
    float cp[8], sp[8];
    #pragma unroll
    for (int r = 0; r < 8; ++r) {
      if (!(r & 2)) {
        const float phi = (par(r & 6) ? -a0 : a0) + (par(r & 3) ? -a1 : a1)
                        + (par(r & 7) ? -A7 : A7);
        float s_, c_;
        __sincosf(phi, &s_, &c_);
        cp[r] = c_;     sp[r] = s_;
        cp[r ^ 2] = c_; sp[r ^ 2] = -s_;
      }
    }
    #pragma unroll
    for (int r = 0; r < 8; ++r) { si[r] = sp[r] * sr[r]; sr[r] = cp[r] * sr[r]; }
  }

  // =============== layer 1: RY in frame L ===============
  {
    float cw[8], sv[8];
    #pragma unroll
    for (int w = 0; w < 8; ++w)
      __sincosf(0.5f * (PI * xs[w] + qw[16 + w]), &sv[w], &cw[w]);

    ry_rr <3,     6, 31>(sr, si, cw[0], sv[0], q);   // u={0,1}   g={1..7}
    ry_rr <6,     3,  0>(sr, si, cw[1], sv[1], q);   // u={1,2}   g={0,1}
    ry_mix<4, 1,  7,  0>(sr, si, cw[2], sv[2], q);   // u={2,3}   g={0,1,2}
    ry_ll <3,     7,  1>(sr, si, cw[3], sv[3], q);   // u={3,4}   g={0..3}
    ry_ll <6,     7,  3>(sr, si, cw[4], sv[4], q);   // u={4,5}   g={0..4}
    ry_ll <12,    7,  7>(sr, si, cw[5], sv[5], q);   // u={5,6}   g={0..5}
    ry_ll <24,    7, 15>(sr, si, cw[6], sv[6], q);   // u={6,7}   g={0..6}
    ry_mix<3, 16, 7, 31>(sr, si, cw[7], sv[7], q);   // u={0,1,7} g={0..7}
  }

  // ===== lazy CNOT #2 ; RZ layer 1 in frame L^2 =====
  // rows of L^2 -> reg groups: a0(mask3), A5={a1,a3,a5,a7}(mask5), A2={a2,a4,a6}(mask2)
  {
    const float h0 = 0.5f * qw[24], h1 = 0.5f * qw[25];
    const float h2 = 0.5f * qw[26], h3 = 0.5f * qw[27];
    const float h4 = 0.5f * qw[28], h5 = 0.5f * qw[29];
    const float h6 = 0.5f * qw[30], h7 = 0.5f * qw[31];
    const float a0 = par(q & 21) ? h0 : -h0;
    const float A5 = (par(q & 31) ? h1 : -h1) + (par(q & 30) ? h3 : -h3)
                   + (par(q & 26) ? h5 : -h5) + (par(q & 10) ? h7 : -h7);
    const float A2 = (par(q & 31) ? h2 : -h2) + (par(q & 29) ? h4 : -h4)
                   + (par(q & 21) ? h6 : -h6);
    // phi[r] = a0*sg(r&3) + A5*sg(r&5) + A2*sg(r&2); phi[r^6] = -phi[r]
    float cp[8], sp[8];
    #pragma unroll
    for (int r = 0; r < 4; ++r) {
      const float phi = (par(r & 3) ? -a0 : a0) + (par(r & 5) ? -A5 : A5)
                      + (par(r & 2) ? -A2 : A2);
      float s_, c_;
      __sincosf(phi, &s_, &c_);
      cp[r] = c_;     sp[r] = s_;
      cp[r ^ 6] = c_; sp[r ^ 6] = -s_;
    }
    #pragma unroll
    for (int r = 0; r < 8; ++r) {
      const float re = sr[r], im = si[r];
      sr[r] = cp[r] * re - sp[r] * im;
      si[r] = cp[r] * im + sp[r] * re;
    }
  }

  // =============== layer 2: RY in frame L^2 ===============
  {
    float cw[8], sv[8];
    #pragma unroll
    for (int w = 0; w < 8; ++w)
      __sincosf(0.5f * (PI * xs[w] + qw[32 + w]), &sv[w], &cw[w]);

    ry_rr <5,     3, 21>(sr, si, cw[0], sv[0], q);   // u={0,2}   g={0,1,3,5,7}
    ry_mix<2, 1,  5, 31>(sr, si, cw[1], sv[1], q);   // u={1,3}   g={0,2,..,7}
    ry_mix<4, 2,  2, 31>(sr, si, cw[2], sv[2], q);   // u={2,4}   g={1,3,..,7}
    ry_ll <5,     5, 30>(sr, si, cw[3], sv[3], q);   // u={3,5}   g={0,2,4..7}
    ry_ll <10,    2, 29>(sr, si, cw[4], sv[4], q);   // u={4,6}   g={1,3,5,6,7}
    ry_ll <20,    5, 26>(sr, si, cw[5], sv[5], q);   // u={5,7}   g={0,2,4,6,7}
    ry_mix<3, 8,  2, 21>(sr, si, cw[6], sv[6], q);   // u={0,1,6} g={1,3,5,7}
    ry_mix<6, 16, 5, 10>(sr, si, cw[7], sv[7], q);   // u={1,2,7} g={0,2,4,6}
  }

  // ===== lazy CNOT #3 ; RZ layer 2 dropped ; measure in frame L^3 =====
  // rows of L^3: g''_0={1,4,5} -> reg 2, lane 6 ; g''_1={1,2,4,6} -> reg 6, lane 10
  //              g''_2={2,3,5,7} -> reg 4, lane 21
  float z0 = 0.f, z1 = 0.f, z2 = 0.f;
  #pragma unroll
  for (int r = 0; r < 8; ++r) {
    const float p = sr[r] * sr[r] + si[r] * si[r];
    z0 += par(r & 2) ? -p : p;
    z1 += par(r & 6) ? -p : p;
    z2 += par(r & 4) ? -p : p;
  }
  if (par(q & 6))  z0 = -z0;
  if (par(q & 10)) z1 = -z1;
  if (par(q & 21)) z2 = -z2;

  // 32-lane butterfly sum (DPP for 1,2,4,8; swizzle for 16)
  z0 += xl<1>(z0);  z1 += xl<1>(z1);  z2 += xl<1>(z2);
  z0 += xl<2>(z0);  z1 += xl<2>(z1);  z2 += xl<2>(z2);
  z0 += xl<4>(z0);  z1 += xl<4>(z1);  z2 += xl<4>(z2);
  z0 += xl<8>(z0);  z1 += xl<8>(z1);  z2 += xl<8>(z2);
  z0 += xl<16>(z0); z1 += xl<16>(z1); z2 += xl<16>(z2);

  if (q < NC) {
    out[elem * NC + q] = b[q] + W[q * 3 + 0] * z0 + W[q * 3 + 1] * z1
                              + W[q * 3 + 2] * z2;
  }
}

extern "C" void kernel_launch(void* const* d_in, const int* in_sizes, int n_in,
                              void* d_out, int out_size, void* d_ws, size_t ws_size,
                              hipStream_t stream) {
  const float* x  = (const float*)d_in[0];
  const float* qw = (const float*)d_in[1];
  const float* W  = (const float*)d_in[2];
  const float* b  = (const float*)d_in[3];
  float* out = (float*)d_out;

  dim3 grid(BATCH / 8);   // 8 elements per 256-thread block, 8192 waves total
  vqc_kernel<<<grid, 256, 0, stream>>>(x, qw, W, b, out);
}

// Round 7
// 22.050 us; speedup vs baseline: 1.0404x; 1.0404x over previous
//
#include <hip/hip_runtime.h>
#include <math.h>

#define NQ 8
#define NL 3
#define NC 3
#define BATCH 16384

// Layout l=4, IDENTITY storage basis: 16 lanes/element, 16 complex amps/thread.
// Amp index t[7:0]: bits 0..3 = reg r (wires 0..3), bits 4..7 = lane q (wires 4..7).
// Lazy CNOT frames (round-5-verified machinery, M=I): after k chains the frame
// is A=L^k; a gate on wire w acts along storage direction u = L^{-k} e_w with
// sign row g = row_w(L^k). No CNOT data movement at all.
//   L: B0=b1^..^b7, Bk=b0^..^bk.
//   L^-1 cols: u0={0,1}, uk={k,k+1} (k=1..6), u7={0,1,7}.
//   L^2 rows: {0,1,3,5,7},{0,2..7},{1,3..7},{0,2,4..7},{1,3,5,6,7},
//             {0,2,4,6,7},{1,3,5,7},{0,2,4,6}
//   L^-2 cols: {0,2},{1,3},{2,4},{3,5},{4,6},{5,7},{0,1,6},{1,2,7}
//   L^3 rows (meas): {1,4,5},{1,2,4,6},{2,3,5,7}
// All lane exchanges have masks 1..15 -> pure DPP. ZERO DS-pipe instructions.

__device__ __forceinline__ int par(int x) { return __popc(x) & 1; }

template<int CTRL>
__device__ __forceinline__ float dppmov(float v) {
  return __builtin_bit_cast(float,
    __builtin_amdgcn_update_dpp(0, __builtin_bit_cast(int, v), CTRL, 0xF, 0xF, true));
}

// exchange with lane (q ^ M), M in 1..15 — all DPP
template<int M>
__device__ __forceinline__ float xl(float v) {
  static_assert(M > 0 && M < 16, "DPP-only exchange");
  constexpr int hi = M & 12;
  constexpr int first = (hi == 0) ? 0 : (hi == 4) ? 0x141      // row_half_mirror = xor7
                        : (hi == 8) ? 0x128                    // row_ror:8      = xor8
                        : 0x140;                               // row_mirror     = xor15
  constexpr int qx = (hi == 4 || hi == 12) ? ((M & 3) ^ 3) : (M & 3);
  constexpr int qc = (qx == 1) ? 0xB1 : (qx == 2) ? 0x4E : 0x1B;
  float t = v;
  if constexpr (first != 0) t = dppmov<first>(t);
  if constexpr (qx != 0)    t = dppmov<qc>(t);
  return t;
}

// ---- RY gate templates (round-5-verified sign conventions; <g,u>=1 always) ----

template<int UREG, int GREG, int GLANE>
__device__ __forceinline__ void ry_rr(float (&sr)[16], float (&si)[16],
                                      float c, float s, int q) {
  static_assert((__builtin_popcount(UREG & GREG) & 1) == 1, "<g,u>!=1");
  const float sl = par(q & GLANE) ? s : -s;
  #pragma unroll
  for (int rA = 0; rA < 16; ++rA) {
    if (rA < (rA ^ UREG)) {
      const int rB = rA ^ UREG;
      const float FA = (__builtin_popcount(rA & GREG) & 1) ? -sl : sl;
      const float ar = sr[rA], ai = si[rA];
      sr[rA] = c * ar + FA * sr[rB];
      si[rA] = c * ai + FA * si[rB];
      sr[rB] = c * sr[rB] - FA * ar;
      si[rB] = c * si[rB] - FA * ai;
    }
  }
}

template<int ULANE, int GREG, int GLANE>
__device__ __forceinline__ void ry_ll(float (&sr)[16], float (&si)[16],
                                      float c, float s, int q) {
  static_assert((__builtin_popcount(ULANE & GLANE) & 1) == 1, "<g,u>!=1");
  const float sl = par(q & GLANE) ? s : -s;
  #pragma unroll
  for (int r = 0; r < 16; ++r) {
    const float xr = xl<ULANE>(sr[r]);
    const float xi = xl<ULANE>(si[r]);
    const float F  = (__builtin_popcount(r & GREG) & 1) ? -sl : sl;
    sr[r] = c * sr[r] + F * xr;
    si[r] = c * si[r] + F * xi;
  }
}

template<int UREG, int ULANE, int GREG, int GLANE>
__device__ __forceinline__ void ry_mix(float (&sr)[16], float (&si)[16],
                                       float c, float s, int q) {
  static_assert(((__builtin_popcount(UREG & GREG) + __builtin_popcount(ULANE & GLANE)) & 1) == 1,
                "<g,u>!=1");
  constexpr int RFLIP = __builtin_popcount(GREG & UREG) & 1;
  const float sl = par(q & GLANE) ? s : -s;
  #pragma unroll
  for (int rA = 0; rA < 16; ++rA) {
    if (rA < (rA ^ UREG)) {
      const int rB = rA ^ UREG;
      const float pBr = xl<ULANE>(sr[rB]);
      const float pBi = xl<ULANE>(si[rB]);
      const float pAr = xl<ULANE>(sr[rA]);
      const float pAi = xl<ULANE>(si[rA]);
      const float FA = (__builtin_popcount(rA & GREG) & 1) ? -sl : sl;
      const float FB = RFLIP ? -FA : FA;
      sr[rA] = c * sr[rA] + FA * pBr;
      si[rA] = c * si[rA] + FA * pBi;
      sr[rB] = c * sr[rB] + FB * pAr;
      si[rB] = c * si[rB] + FB * pAi;
    }
  }
}

__global__ __launch_bounds__(256, 4) void vqc_kernel(
    const float* __restrict__ x, const float* __restrict__ qw,
    const float* __restrict__ W, const float* __restrict__ b,
    float* __restrict__ out)
{
  const int tid  = threadIdx.x;
  const int q    = tid & 15;
  const int elem = blockIdx.x * 16 + (tid >> 4);

  const float PI = 3.14159265358979323846f;

  float xs[8];
  {
    const float4 x0 = *(const float4*)(x + elem * 8);
    const float4 x1 = *(const float4*)(x + elem * 8 + 4);
    xs[0] = x0.x; xs[1] = x0.y; xs[2] = x0.z; xs[3] = x0.w;
    xs[4] = x1.x; xs[5] = x1.y; xs[6] = x1.z; xs[7] = x1.w;
  }

  float sr[16], si[16];

  // ===== layer 0 RY: product state (real) — round-4-verified identity map =====
  {
    float cw[8], sw[8];
    #pragma unroll
    for (int w = 0; w < 8; ++w)
      __sincosf(0.5f * (PI * xs[w] + qw[w]), &sw[w], &cw[w]);

    float P = ((q & 1) ? sw[4] : cw[4]);
    P      *= ((q & 2) ? sw[5] : cw[5]);
    P      *= ((q & 4) ? sw[6] : cw[6]);
    P      *= ((q & 8) ? sw[7] : cw[7]);
    sr[0] = P * cw[0];
    sr[1] = P * sw[0];
    #pragma unroll
    for (int r = 0; r < 2; ++r) { sr[r + 2] = sr[r] * sw[1]; sr[r] *= cw[1]; }
    #pragma unroll
    for (int r = 0; r < 4; ++r) { sr[r + 4] = sr[r] * sw[2]; sr[r] *= cw[2]; }
    #pragma unroll
    for (int r = 0; r < 8; ++r) { sr[r + 8] = sr[r] * sw[3]; sr[r] *= cw[3]; }
  }

  // ===== lazy CNOT #1 ; RZ layer 0 in frame L (real -> complex) =====
  // rows of L: w0:(r14,l15) w1:(r3,0) w2:(r7,0) w3:(r15,0)
  //            w4:(r15,l1) w5:(r15,l3) w6:(r15,l7) w7:(r15,l15)
  {
    const float h0 = 0.5f * qw[8],  h1 = 0.5f * qw[9];
    const float h2 = 0.5f * qw[10], h3 = 0.5f * qw[11];
    const float h4 = 0.5f * qw[12], h5 = 0.5f * qw[13];
    const float h6 = 0.5f * qw[14], h7 = 0.5f * qw[15];
    const float c0 = par(q & 15) ? h0 : -h0;
    const float c1 = -h1;
    const float c2 = -h2;
    const float A  = -h3 + (par(q & 1) ? h4 : -h4) + (par(q & 3)  ? h5 : -h5)
                         + (par(q & 7) ? h6 : -h6) + (par(q & 15) ? h7 : -h7);
    // phi[r] = sg(r&14)c0 + sg(r&3)c1 + sg(r&7)c2 + sg(r&15)A ; phi[r^2]=-phi[r]
    float cp[16], sp[16];
    #pragma unroll
    for (int r = 0; r < 16; ++r) {
      if (!(r & 2)) {
        const float phi = ((__builtin_popcount(r & 14) & 1) ? -c0 : c0)
                        + ((__builtin_popcount(r & 3)  & 1) ? -c1 : c1)
                        + ((__builtin_popcount(r & 7)  & 1) ? -c2 : c2)
                        + ((__builtin_popcount(r & 15) & 1) ? -A  : A);
        float s_, c_;
        __sincosf(phi, &s_, &c_);
        cp[r] = c_;     sp[r] = s_;
        cp[r ^ 2] = c_; sp[r ^ 2] = -s_;
      }
    }
    #pragma unroll
    for (int r = 0; r < 16; ++r) { si[r] = sp[r] * sr[r]; sr[r] = cp[r] * sr[r]; }
  }

  // ===== layer 1 RY (frame L) =====
  // u = L^-1 e_w ; g = row_w(L)
  {
    float cw[8], sw[8];
    #pragma unroll
    for (int w = 0; w < 8; ++w)
      __sincosf(0.5f * (PI * xs[w] + qw[16 + w]), &sw[w], &cw[w]);

    ry_rr <3,    14, 15>(sr, si, cw[0], sw[0], q);   // u={0,1}   g={1..7}
    ry_rr <6,     3,  0>(sr, si, cw[1], sw[1], q);   // u={1,2}   g={0,1}
    ry_rr <12,    7,  0>(sr, si, cw[2], sw[2], q);   // u={2,3}   g={0,1,2}
    ry_mix<8, 1, 15,  0>(sr, si, cw[3], sw[3], q);   // u={3,4}   g={0..3}
    ry_ll <3,    15,  1>(sr, si, cw[4], sw[4], q);   // u={4,5}   g={0..4}
    ry_ll <6,    15,  3>(sr, si, cw[5], sw[5], q);   // u={5,6}   g={0..5}
    ry_ll <12,   15,  7>(sr, si, cw[6], sw[6], q);   // u={6,7}   g={0..6}
    ry_mix<3, 8, 15, 15>(sr, si, cw[7], sw[7], q);   // u={0,1,7} g={0..7}
  }

  // ===== lazy CNOT #2 ; RZ layer 1 in frame L^2 =====
  // rows: w0:(r11,l10) w1:(r13,l15) w2:(r10,l15) w3:(r5,l15)
  //       w4:(r10,l14) w5:(r5,l13) w6:(r10,l10) w7:(r5,l5)
  {
    const float h0 = 0.5f * qw[24], h1 = 0.5f * qw[25];
    const float h2 = 0.5f * qw[26], h3 = 0.5f * qw[27];
    const float h4 = 0.5f * qw[28], h5 = 0.5f * qw[29];
    const float h6 = 0.5f * qw[30], h7 = 0.5f * qw[31];
    const float d0 = par(q & 10) ? h0 : -h0;
    const float d1 = par(q & 15) ? h1 : -h1;
    const float d2 = (par(q & 15) ? h2 : -h2) + (par(q & 14) ? h4 : -h4)
                   + (par(q & 10) ? h6 : -h6);
    const float d3 = (par(q & 15) ? h3 : -h3) + (par(q & 13) ? h5 : -h5)
                   + (par(q & 5)  ? h7 : -h7);
    // phi[r] = sg(r&11)d0 + sg(r&13)d1 + sg(r&10)d2 + sg(r&5)d3 ; phi[r^6]=-phi[r]
    float cp[16], sp[16];
    #pragma unroll
    for (int r = 0; r < 16; ++r) {
      if (!(r & 2)) {
        const float phi = ((__builtin_popcount(r & 11) & 1) ? -d0 : d0)
                        + ((__builtin_popcount(r & 13) & 1) ? -d1 : d1)
                        + ((__builtin_popcount(r & 10) & 1) ? -d2 : d2)
                        + ((__builtin_popcount(r & 5)  & 1) ? -d3 : d3);
        float s_, c_;
        __sincosf(phi, &s_, &c_);
        cp[r] = c_;     sp[r] = s_;
        cp[r ^ 6] = c_; sp[r ^ 6] = -s_;
      }
    }
    #pragma unroll
    for (int r = 0; r < 16; ++r) {
      const float re = sr[r], im = si[r];
      sr[r] = cp[r] * re - sp[r] * im;
      si[r] = cp[r] * im + sp[r] * re;
    }
  }

  // ===== layer 2 RY (frame L^2) =====
  // u = L^-2 e_w ; g = row_w(L^2)
  {
    float cw[8], sw[8];
    #pragma unroll
    for (int w = 0; w < 8; ++w)
      __sincosf(0.5f * (PI * xs[w] + qw[32 + w]), &sw[w], &cw[w]);

    ry_rr <5,    11, 10>(sr, si, cw[0], sw[0], q);   // u={0,2}   g={0,1,3,5,7}
    ry_rr <10,   13, 15>(sr, si, cw[1], sw[1], q);   // u={1,3}   g={0,2..7}
    ry_mix<4, 1, 10, 15>(sr, si, cw[2], sw[2], q);   // u={2,4}   g={1,3..7}
    ry_mix<8, 2,  5, 15>(sr, si, cw[3], sw[3], q);   // u={3,5}   g={0,2,4..7}
    ry_ll <5,    10, 14>(sr, si, cw[4], sw[4], q);   // u={4,6}   g={1,3,5,6,7}
    ry_ll <10,    5, 13>(sr, si, cw[5], sw[5], q);   // u={5,7}   g={0,2,4,6,7}
    ry_mix<3, 4, 10, 10>(sr, si, cw[6], sw[6], q);   // u={0,1,6} g={1,3,5,7}
    ry_mix<6, 8,  5,  5>(sr, si, cw[7], sw[7], q);   // u={1,2,7} g={0,2,4,6}
  }

  // ===== lazy CNOT #3 ; RZ2 dropped ; measure in frame L^3 =====
  // rows of L^3: z0:{1,4,5}->(r2,l3)  z1:{1,2,4,6}->(r6,l5)  z2:{2,3,5,7}->(r12,l10)
  float z0 = 0.f, z1 = 0.f, z2 = 0.f;
  #pragma unroll
  for (int r = 0; r < 16; ++r) {
    const float p = sr[r] * sr[r] + si[r] * si[r];
    z0 += (__popc(r & 2)  & 1) ? -p : p;
    z1 += (__popc(r & 6)  & 1) ? -p : p;
    z2 += (__popc(r & 12) & 1) ? -p : p;
  }
  if (par(q & 3))  z0 = -z0;
  if (par(q & 5))  z1 = -z1;
  if (par(q & 10)) z2 = -z2;

  // 16-lane butterfly (all DPP)
  z0 += xl<1>(z0); z1 += xl<1>(z1); z2 += xl<1>(z2);
  z0 += xl<2>(z0); z1 += xl<2>(z1); z2 += xl<2>(z2);
  z0 += xl<4>(z0); z1 += xl<4>(z1); z2 += xl<4>(z2);
  z0 += xl<8>(z0); z1 += xl<8>(z1); z2 += xl<8>(z2);

  if (q < NC) {
    out[elem * NC + q] = b[q] + W[q * 3 + 0] * z0 + W[q * 3 + 1] * z1
                              + W[q * 3 + 2] * z2;
  }
}

extern "C" void kernel_launch(void* const* d_in, const int* in_sizes, int n_in,
                              void* d_out, int out_size, void* d_ws, size_t ws_size,
                              hipStream_t stream) {
  const float* x  = (const float*)d_in[0];
  const float* qw = (const float*)d_in[1];
  const float* W  = (const float*)d_in[2];
  const float* b  = (const float*)d_in[3];
  float* out = (float*)d_out;

  dim3 grid(BATCH / 16);   // 16 elements per 256-thread block
  vqc_kernel<<<grid, 256, 0, stream>>>(x, qw, W, b, out);
}